// Round 9
// baseline (83.664 us; speedup 1.0000x reference)
//
#include <hip/hip_runtime.h>
#include <math.h>

#define B_    32
#define P_    32
#define V_    200
#define NF_   4
#define TR_   80
#define NROT_ 16
#define NLIG_ 7
#define NTH_  640

#define WSLOTS 33              // absolute lattice window n in [-24, 8]
#define CSTR   (WSLOTS * 25)   // 825 floats per table
#define RSTR   84              // ring per-f stride (bank-spread, 16B aligned)

// f32(2*pi) and f32(2*pi/16): DELTA_F*16 == TWO_PI_F exactly.
static constexpr float TWO_PI_F  = 6.2831854820251465f;
static constexpr float DELTA_F   = 0.39269909262657166f;

// ---------------------------------------------------------------------------
// Conv layer via exact-wrap cumulative theta-lattice tables (see R5 header).
// R8: conv phase is LDS-pipe bound -> u-blocking x4: thread owns
// (rot-pair g, f, u-quad), reads desc as 40 b128 broadcasts (was 160) and
// W_conv as float4 over u from L2; ring rows padded to stride 84 so the 4
// broadcast address groups per wave hit distinct banks.  Table-zero b128.
// ---------------------------------------------------------------------------
__global__ __launch_bounds__(NTH_, 5) void masif_conv_kernel(
    const float* __restrict__ feat, const float* __restrict__ rho,
    const float* __restrict__ theta, const float* __restrict__ mask,
    const float* __restrict__ mu_rho, const float* __restrict__ sigma_rho,
    const float* __restrict__ mu_theta, const float* __restrict__ sigma_theta,
    const float* __restrict__ W_conv, const float* __restrict__ b_conv,
    const float* __restrict__ W1, const float* __restrict__ b1,
    const float* __restrict__ bn1_g, const float* __restrict__ bn1_b,
    const float* __restrict__ bn1_m, const float* __restrict__ bn1_v,
    const float* __restrict__ bn2_g, const float* __restrict__ bn2_b,
    const float* __restrict__ bn2_m, const float* __restrict__ bn2_v,
    float* __restrict__ x2out)
{
    __shared__ __align__(16) float s_C[16 * CSTR];   // 52800 B (+overlays)
    __shared__ __align__(16) float s_V[V_][12];      //  9600 B
    __shared__ float s_offs[NROT_];
    __shared__ float s_mu[5], s_isr[5];
    __shared__ float s_ist1;
    __shared__ int   s_cnt[16], s_start[17];
    __shared__ int   s_whist[4][16];

    const int tid = threadIdx.x;
    const int bp  = blockIdx.x;
    const size_t vb = (size_t)bp * V_;

    // staging overlay inside s_C (dead before tables are zeroed/written)
    float*  stg_th  = s_C;                    // [200]
    float*  stg_rho = s_C + 256;              // [200]
    float*  stg_msk = s_C + 512;              // [200]
    float4* stg_f4  = (float4*)(s_C + 768);   // [200] float4
    int*    s_code  = (int*)(s_C + 1600);     // [200]

    for (int i = tid; i < V_; i += NTH_) {
        stg_th[i]  = theta[vb + i];
        stg_rho[i] = rho[vb + i];
        stg_msk[i] = mask[vb + i];
        stg_f4[i]  = ((const float4*)(feat + vb * NF_))[i];
    }
    if (tid < NROT_) s_offs[tid] = (float)tid * DELTA_F;
    if (tid < 5) {
        s_mu[tid] = mu_rho[tid * 16];
        float sg = sigma_rho[tid * 16];
        s_isr[tid] = 1.0f / (sg * sg + 1e-5f);
    }
    if (tid == 5) { float sg = sigma_theta[0]; s_ist1 = 1.0f / (sg * sg + 1e-5f); }
    if (tid >= 32 && tid < 48) s_cnt[tid - 32] = 0;
    __syncthreads();

    // ---- classify by exact first-wrap rotation r* (bucket = r*-1) ----
    int myb = 0;
    if (tid < V_) {
        float th = stg_th[tid];
        int rs = 16;
        for (int r = 1; r < 16; ++r) {
            if (th + s_offs[r] >= TWO_PI_F) { rs = r; break; }   // exact f32 rule
        }
        myb = rs - 1;                         // 0..15
        s_code[tid] = myb;
        atomicAdd(&s_cnt[myb], 1);
    }
    __syncthreads();
    if (tid == 0) {
        int run = 0;
        for (int k = 0; k < 16; ++k) { s_start[k] = run; run += s_cnt[k]; }
        s_start[16] = run;
    }

    // ---- deterministic rank via ballot (waves 0..3 cover tid<256) ----
    int rkw = 0;
    {
        const unsigned long long below = (1ULL << (tid & 63)) - 1ULL;
        const int wv = tid >> 6;
        for (int b = 0; b < 16; ++b) {
            bool p = (tid < V_) && (myb == b);
            unsigned long long m = __ballot(p);
            if (p) rkw = __popcll(m & below);
            if (wv < 4 && (tid & 63) == b) s_whist[wv][b] = __popcll(m);
        }
    }
    __syncthreads();

    // ---- scatter into bucket-sorted s_V: [R0..R3 | R4 th ch0 ch1 | ch2..4] --
    if (tid < V_) {
        int rk = rkw;
        for (int w = 0; w < (tid >> 6); ++w) rk += s_whist[w][myb];
        int pos = s_start[myb] + rk;
        float th = stg_th[tid];
        float mk = stg_msk[tid];
        float4 f4 = stg_f4[tid];
        float rv = stg_rho[tid];
        float R[5];
        #pragma unroll
        for (int i = 0; i < 5; ++i) {
            float d = rv - s_mu[i];
            R[i] = __expf(-d * d * s_isr[i]);
        }
        *(float4*)&s_V[pos][0] = make_float4(R[0], R[1], R[2], R[3]);
        *(float4*)&s_V[pos][4] = make_float4(R[4], th, f4.x * mk, f4.y * mk);
        *(float4*)&s_V[pos][8] = make_float4(f4.z * mk, f4.w * mk, mk, 0.0f);
    }
    __syncthreads();   // staging overlay dead from here

    // ---- zero all tables (b128) ----
    {
        float4 z4 = make_float4(0.f, 0.f, 0.f, 0.f);
        float4* C4 = (float4*)s_C;
        for (int e = tid; e < 16 * CSTR / 4; e += NTH_) C4[e] = z4;
    }
    __syncthreads();

    // ---- G-table build: team of 40 threads per bucket (table = team) ----
    // active n in [team-25, team-6] (20 slots); stored slot w = n + 24.
    {
        const int team = tid / 40, t40 = tid - team * 40;
        const int cg = t40 >> 3;             // channel 0..4
        const int mq = t40 & 7;              // 8 m-tiles x 3 slots = 24 >= 20
        const float ist = s_ist1;
        float acc[3][5];
        #pragma unroll
        for (int mm = 0; mm < 3; ++mm)
            #pragma unroll
            for (int i = 0; i < 5; ++i) acc[mm][i] = 0.0f;
        const int v0 = s_start[team], v1 = s_start[team + 1];
        const float nbase = (float)(team - 25 + mq * 3);   // n at local l=mq*3
        for (int v = v0; v < v1; ++v) {
            float4 ra = *(const float4*)&s_V[v][0];
            const float r4 = s_V[v][4];
            const float th = s_V[v][5];
            const float ch = s_V[v][6 + cg];
            float A0 = ch * ra.x, A1 = ch * ra.y, A2 = ch * ra.z,
                  A3 = ch * ra.w, A4 = ch * r4;
            #pragma unroll
            for (int mm = 0; mm < 3; ++mm) {
                float q = fmaf(nbase + (float)mm, DELTA_F, th);
                float w = __expf(-q * q * ist);
                acc[mm][0] = fmaf(w, A0, acc[mm][0]);
                acc[mm][1] = fmaf(w, A1, acc[mm][1]);
                acc[mm][2] = fmaf(w, A2, acc[mm][2]);
                acc[mm][3] = fmaf(w, A3, acc[mm][3]);
                acc[mm][4] = fmaf(w, A4, acc[mm][4]);
            }
        }
        #pragma unroll
        for (int mm = 0; mm < 3; ++mm) {
            const int l = mq * 3 + mm;             // local slot 0..23
            const int w = team - 1 + l;            // stored slot
            if (l < 20 && w >= 0 && w < WSLOTS)
                #pragma unroll
                for (int i = 0; i < 5; ++i)
                    s_C[team * CSTR + w * 25 + cg * 5 + i] = acc[mm][i];
        }
    }
    __syncthreads();

    // ---- shift-free prefix: column walk over all 825 element-columns ----
    for (int e = tid; e < CSTR; e += NTH_) {
        float run = s_C[e];                        // table 0 = C[1]
        #pragma unroll
        for (int tk = 1; tk < 16; ++tk) {
            run += s_C[tk * CSTR + e];
            s_C[tk * CSTR + e] = run;
        }
    }
    __syncthreads();

    // ---- rotation loop: half h computes rotations h*8..h*8+7 into REGS ----
    const int half = tid / 320, lt = tid - half * 320;
    const int j1 = lt & 15, ci1 = lt >> 4;        // ci1 = c1*5+i1, 0..19
    const int c1 = ci1 / 5, i1 = ci1 - c1 * 5;
    const int ridx = c1 * RSTR + i1 * 16 + j1;    // ring index (f-stride 84)
    const int sD = ci1, sS = 20 + i1;
    const float* Tb = s_C + 15 * CSTR;
    float dreg[8];

    #pragma unroll
    for (int lr = 0; lr < 8; ++lr) {
        const int r  = half * 8 + lr;
        const int wT = r - j1 + 24;               // [9, 39]
        const bool pT = (wT <= 32);
        const int wTc = pT ? wT : 32;
        const float* Tp = Tb + wTc * 25;
        float tD = Tp[sD], tS = Tp[sS];
        float D = pT ? tD : 0.0f;
        float S = pT ? tS : 0.0f;
        if (r > 0) {
            const float* Cr = s_C + (r - 1) * CSTR;
            const float* Up = Cr + wTc * 25;
            float uD = Up[sD], uS = Up[sS];
            if (pT) { D -= uD; S -= uS; }
            const int wW = wT - 16;               // [-7, 23]
            const bool pW = (wW >= 0);
            const int wWc = pW ? wW : 0;
            const float* Wp = Cr + wWc * 25;
            float wD = Wp[sD], wS = Wp[sS];
            if (pW) { D += wD; S += wS; }
        }
        dreg[lr] = D / (S + 1e-5f);
    }
    __syncthreads();   // all table reads done -> s_C region reusable

    // ---- overlays in dead table region ----
    float* ring    = s_C;                 // [16][4*RSTR=336] = 5376 floats
    float* s_pool2 = s_C + 5376;          // [8][320] = 2560
    float* s_x1    = s_C + 7936;          // [320]
    float* s_part  = s_C + 8256;          // [640]

    #pragma unroll
    for (int lr = 0; lr < 8; ++lr)
        ring[(half * 8 + lr) * (4 * RSTR) + ridx] = dreg[lr];
    __syncthreads();

    // ---- conv, u-blocked x4: thread = (rot-pair g, f, u-quad) ----
    {
        const int g  = tid / 80;              // rotations 2g, 2g+1
        const int s  = tid - g * 80;
        const int cf = s / 20;                // f
        const int uq = s - cf * 20;
        const int u0 = uq * 4;
        const float* Wf = W_conv + (size_t)cf * TR_ * TR_ + u0;  // W[cf][k][u0..3]
        const float* r0 = ring + (2 * g) * (4 * RSTR) + cf * RSTR;
        const float* r1 = r0 + (4 * RSTR);
        float4 a0 = make_float4(0.f, 0.f, 0.f, 0.f);
        float4 a1 = make_float4(0.f, 0.f, 0.f, 0.f);
        #pragma unroll 4
        for (int kq = 0; kq < 20; ++kq) {
            const int k = kq * 4;
            float4 d0 = *(const float4*)&r0[k];
            float4 d1 = *(const float4*)&r1[k];
            float4 w0 = *(const float4*)&Wf[(size_t)(k + 0) * TR_];
            float4 w1 = *(const float4*)&Wf[(size_t)(k + 1) * TR_];
            float4 w2 = *(const float4*)&Wf[(size_t)(k + 2) * TR_];
            float4 w3 = *(const float4*)&Wf[(size_t)(k + 3) * TR_];
            a0.x = fmaf(d0.x,w0.x, fmaf(d0.y,w1.x, fmaf(d0.z,w2.x, fmaf(d0.w,w3.x, a0.x))));
            a0.y = fmaf(d0.x,w0.y, fmaf(d0.y,w1.y, fmaf(d0.z,w2.y, fmaf(d0.w,w3.y, a0.y))));
            a0.z = fmaf(d0.x,w0.z, fmaf(d0.y,w1.z, fmaf(d0.z,w2.z, fmaf(d0.w,w3.z, a0.z))));
            a0.w = fmaf(d0.x,w0.w, fmaf(d0.y,w1.w, fmaf(d0.z,w2.w, fmaf(d0.w,w3.w, a0.w))));
            a1.x = fmaf(d1.x,w0.x, fmaf(d1.y,w1.x, fmaf(d1.z,w2.x, fmaf(d1.w,w3.x, a1.x))));
            a1.y = fmaf(d1.x,w0.y, fmaf(d1.y,w1.y, fmaf(d1.z,w2.y, fmaf(d1.w,w3.y, a1.y))));
            a1.z = fmaf(d1.x,w0.z, fmaf(d1.y,w1.z, fmaf(d1.z,w2.z, fmaf(d1.w,w3.z, a1.z))));
            a1.w = fmaf(d1.x,w0.w, fmaf(d1.y,w1.w, fmaf(d1.z,w2.w, fmaf(d1.w,w3.w, a1.w))));
        }
        float4 m;
        m.x = fmaxf(a0.x, a1.x); m.y = fmaxf(a0.y, a1.y);
        m.z = fmaxf(a0.z, a1.z); m.w = fmaxf(a0.w, a1.w);
        *(float4*)&s_pool2[g * 320 + cf * TR_ + u0] = m;
    }
    __syncthreads();

    // ---- epilogue: maxpool-8 + b_conv + bn1 + relu + W1 + bn2 + relu ----
    if (tid < 320) {
        float best = s_pool2[tid];
        #pragma unroll
        for (int g2 = 1; g2 < 8; ++g2)
            best = fmaxf(best, s_pool2[g2 * 320 + tid]);
        best += b_conv[tid];
        float x1 = (best - bn1_m[tid]) * (bn1_g[tid] * rsqrtf(bn1_v[tid] + 1e-3f))
                   + bn1_b[tid];
        s_x1[tid] = fmaxf(x1, 0.0f);
    }
    __syncthreads();
    {
        const int c = tid / TR_;                 // input chunk 0..7 (40 rows)
        const int ue = tid - c * TR_;
        float p = 0.0f;
        const int i0 = c * 40;
        #pragma unroll 8
        for (int i = i0; i < i0 + 40; ++i)
            p = fmaf(s_x1[i], W1[(size_t)i * TR_ + ue], p);
        s_part[tid] = p;
    }
    __syncthreads();
    if (tid < TR_) {
        float h = b1[tid];
        #pragma unroll
        for (int c = 0; c < 8; ++c) h += s_part[c * TR_ + tid];
        float x2 = (h - bn2_m[tid]) * (bn2_g[tid] * rsqrtf(bn2_v[tid] + 1e-3f))
                   + bn2_b[tid];
        x2out[(size_t)bp * TR_ + tid] = fmaxf(x2, 0.0f);
    }
}

// ---------------------------------------------------------------------------
// Head, stage A: per (b, chunk c of 10 cov rows): cov chunk + W2 partial.
// ---------------------------------------------------------------------------
__global__ __launch_bounds__(256) void masif_head_partial(
    const float* __restrict__ x2,       // [B*P, 80]
    const float* __restrict__ W2,       // [6400, 64]
    float* __restrict__ hpart)          // [B, 8, 64]
{
    __shared__ __align__(16) float s_x[P_ * TR_];
    __shared__ __align__(16) float s_cov[10 * TR_];
    __shared__ float s_red[4][64];

    const int tid = threadIdx.x;
    const int b = blockIdx.x >> 3, c = blockIdx.x & 7;

    for (int i = tid; i < P_ * TR_; i += 256)
        s_x[i] = x2[(size_t)b * P_ * TR_ + i];
    __syncthreads();

    for (int o = tid; o < 800; o += 256) {
        int il = o / TR_, j = o - il * TR_;
        int i = c * 10 + il;
        float s = 0.0f;
        #pragma unroll 4
        for (int p = 0; p < P_; ++p)
            s = fmaf(s_x[p * TR_ + i], s_x[p * TR_ + j], s);
        s_cov[o] = s * (1.0f / (float)P_);
    }
    __syncthreads();

    {
        const int o = tid & 63, sub = tid >> 6;
        float acc = 0.0f;
        const int q0 = sub * 200;
        const size_t gbase = (size_t)(c * 800) * 64 + o;
        #pragma unroll 8
        for (int q = q0; q < q0 + 200; ++q)
            acc = fmaf(s_cov[q], W2[gbase + (size_t)q * 64], acc);
        s_red[sub][o] = acc;
    }
    __syncthreads();
    if (tid < 64)
        hpart[(size_t)b * 512 + c * 64 + tid] =
            s_red[0][tid] + s_red[1][tid] + s_red[2][tid] + s_red[3][tid];
}

// ---------------------------------------------------------------------------
// Head, stage B: combine chunks, relu, bn3, W3.
// ---------------------------------------------------------------------------
__global__ __launch_bounds__(64) void masif_head_final(
    const float* __restrict__ hpart,
    const float* __restrict__ b2,
    const float* __restrict__ bn3_g, const float* __restrict__ bn3_b,
    const float* __restrict__ bn3_m, const float* __restrict__ bn3_v,
    const float* __restrict__ W3, const float* __restrict__ b3,
    float* __restrict__ out)
{
    __shared__ float s_h[64];
    const int tid = threadIdx.x;
    const int b = blockIdx.x;

    float h = b2[tid];
    #pragma unroll
    for (int c = 0; c < 8; ++c) h += hpart[(size_t)b * 512 + c * 64 + tid];
    h = fmaxf(h, 0.0f);
    s_h[tid] = (h - bn3_m[tid]) * (bn3_g[tid] * rsqrtf(bn3_v[tid] + 1e-3f))
               + bn3_b[tid];
    __syncthreads();

    if (tid < NLIG_) {
        float y = b3[tid];
        #pragma unroll
        for (int k = 0; k < 64; ++k)
            y = fmaf(s_h[k], W3[k * NLIG_ + tid], y);
        out[b * NLIG_ + tid] = y;
    }
}

// ---------------------------------------------------------------------------
extern "C" void kernel_launch(void* const* d_in, const int* in_sizes, int n_in,
                              void* d_out, int out_size, void* d_ws, size_t ws_size,
                              hipStream_t stream)
{
    const float* feat      = (const float*)d_in[0];
    const float* rho       = (const float*)d_in[1];
    const float* theta     = (const float*)d_in[2];
    const float* mask      = (const float*)d_in[3];
    const float* mu_rho    = (const float*)d_in[4];
    const float* sigma_rho = (const float*)d_in[5];
    const float* mu_theta  = (const float*)d_in[6];
    const float* sigma_th  = (const float*)d_in[7];
    const float* W_conv    = (const float*)d_in[8];
    const float* b_conv    = (const float*)d_in[9];
    const float* W1        = (const float*)d_in[10];
    const float* b1        = (const float*)d_in[11];
    const float* bn1_g     = (const float*)d_in[12];
    const float* bn1_b     = (const float*)d_in[13];
    const float* bn1_m     = (const float*)d_in[14];
    const float* bn1_v     = (const float*)d_in[15];
    const float* bn2_g     = (const float*)d_in[16];
    const float* bn2_b     = (const float*)d_in[17];
    const float* bn2_m     = (const float*)d_in[18];
    const float* bn2_v     = (const float*)d_in[19];
    const float* W2        = (const float*)d_in[20];
    const float* b2        = (const float*)d_in[21];
    const float* bn3_g     = (const float*)d_in[22];
    const float* bn3_b     = (const float*)d_in[23];
    const float* bn3_m     = (const float*)d_in[24];
    const float* bn3_v     = (const float*)d_in[25];
    const float* W3        = (const float*)d_in[26];
    const float* b3        = (const float*)d_in[27];

    float* x2ws  = (float*)d_ws;                          // [1024*80]
    float* hpart = (float*)d_ws + (size_t)B_ * P_ * TR_;  // [32*8*64]

    masif_conv_kernel<<<dim3(B_ * P_), dim3(NTH_), 0, stream>>>(
        feat, rho, theta, mask, mu_rho, sigma_rho, mu_theta, sigma_th,
        W_conv, b_conv, W1, b1,
        bn1_g, bn1_b, bn1_m, bn1_v, bn2_g, bn2_b, bn2_m, bn2_v, x2ws);

    masif_head_partial<<<dim3(B_ * 8), dim3(256), 0, stream>>>(x2ws, W2, hpart);

    masif_head_final<<<dim3(B_), dim3(64), 0, stream>>>(
        hpart, b2, bn3_g, bn3_b, bn3_m, bn3_v, W3, b3, (float*)d_out);
}

// Round 10
// 67.842 us; speedup vs baseline: 1.2332x; 1.2332x over previous
//
#include <hip/hip_runtime.h>
#include <math.h>

#define B_    32
#define P_    32
#define V_    200
#define NF_   4
#define TR_   80
#define NROT_ 16
#define NLIG_ 7
#define NTH_  1024
#define PKT_  512              // threads per pocket (2 pockets per block)

#define WSLOTS 33              // absolute lattice window n in [-24, 8]
#define CSTR   (WSLOTS * 25)   // 825 floats per table
#define CTOT   (16 * CSTR)     // 13200 floats per pocket table block
#define RSTR   84              // ring per-f stride

// f32(2*pi) and f32(2*pi/16): DELTA_F*16 == TWO_PI_F exactly.
static constexpr float TWO_PI_F  = 6.2831854820251465f;
static constexpr float DELTA_F   = 0.39269909262657166f;

// ---------------------------------------------------------------------------
// Conv layer via exact-wrap cumulative theta-lattice tables (see R5 header).
// R9: POCKET-PAIRING.  Evidence (R7: LDS cut -> no co-residency; R8: LDS-op
// cut -> no speedup, VALUBusy fell) says the kernel is latency-bound inside
// ONE resident block.  Fix: one 1024-thread workgroup = 2 independent pockets
// (per-pocket LDS images, shared barriers) -> guaranteed 16 waves/CU, grid
// 512 -> 2 dispatch rounds instead of 4.  Phase maps adapted to 512 thr/pkt.
// LDS ~125.7 KB/block.
// ---------------------------------------------------------------------------
__global__ __launch_bounds__(NTH_, 4) void masif_conv_kernel(
    const float* __restrict__ feat, const float* __restrict__ rho,
    const float* __restrict__ theta, const float* __restrict__ mask,
    const float* __restrict__ mu_rho, const float* __restrict__ sigma_rho,
    const float* __restrict__ mu_theta, const float* __restrict__ sigma_theta,
    const float* __restrict__ W_conv, const float* __restrict__ b_conv,
    const float* __restrict__ W1, const float* __restrict__ b1,
    const float* __restrict__ bn1_g, const float* __restrict__ bn1_b,
    const float* __restrict__ bn1_m, const float* __restrict__ bn1_v,
    const float* __restrict__ bn2_g, const float* __restrict__ bn2_b,
    const float* __restrict__ bn2_m, const float* __restrict__ bn2_v,
    float* __restrict__ x2out)
{
    __shared__ __align__(16) float s_C[2][CTOT];     // 105600 B (+overlays)
    __shared__ __align__(16) float s_V[2][V_][12];   //  19200 B
    __shared__ float s_offs[NROT_];
    __shared__ float s_mu[5], s_isr[5];
    __shared__ float s_ist1;
    __shared__ int   s_cnt[2][16], s_start[2][17];
    __shared__ int   s_whist[2][4][16];

    const int tid = threadIdx.x;
    const int pk  = tid >> 9;            // pocket 0/1
    const int lt  = tid & 511;           // lane within pocket
    const int bp  = blockIdx.x * 2 + pk; // pocket id
    const size_t vb = (size_t)bp * V_;

    float* Cp = s_C[pk];                 // pocket table block

    // staging overlay inside Cp (dead before tables are zeroed/written)
    float*  stg_th  = Cp;                    // [200]
    float*  stg_rho = Cp + 256;              // [200]
    float*  stg_msk = Cp + 512;              // [200]
    float4* stg_f4  = (float4*)(Cp + 768);   // [200] float4

    for (int i = lt; i < V_; i += PKT_) {
        stg_th[i]  = theta[vb + i];
        stg_rho[i] = rho[vb + i];
        stg_msk[i] = mask[vb + i];
        stg_f4[i]  = ((const float4*)(feat + vb * NF_))[i];
    }
    if (tid < NROT_) s_offs[tid] = (float)tid * DELTA_F;
    if (tid < 5) {
        s_mu[tid] = mu_rho[tid * 16];
        float sg = sigma_rho[tid * 16];
        s_isr[tid] = 1.0f / (sg * sg + 1e-5f);
    }
    if (tid == 5) { float sg = sigma_theta[0]; s_ist1 = 1.0f / (sg * sg + 1e-5f); }
    if (tid >= 64 && tid < 96) ((int*)s_cnt)[tid - 64] = 0;
    __syncthreads();

    // ---- classify by exact first-wrap rotation r* (bucket = r*-1) ----
    int myb = 0;
    if (lt < V_) {
        float th = stg_th[lt];
        int rs = 16;
        for (int r = 1; r < 16; ++r) {
            if (th + s_offs[r] >= TWO_PI_F) { rs = r; break; }   // exact f32 rule
        }
        myb = rs - 1;                         // 0..15
        atomicAdd(&s_cnt[pk][myb], 1);
    }

    // ---- deterministic rank via ballot (pocket waves 0..3 cover lt<256) ----
    int rkw = 0;
    {
        const unsigned long long below = (1ULL << (tid & 63)) - 1ULL;
        const int wv = lt >> 6;               // wave within pocket
        for (int b = 0; b < 16; ++b) {
            bool p = (lt < V_) && (myb == b);
            unsigned long long m = __ballot(p);
            if (p) rkw = __popcll(m & below);
            if (wv < 4 && (tid & 63) == b) s_whist[pk][wv][b] = __popcll(m);
        }
    }
    __syncthreads();
    if (lt == 0) {
        int run = 0;
        for (int k = 0; k < 16; ++k) { s_start[pk][k] = run; run += s_cnt[pk][k]; }
        s_start[pk][16] = run;
    }
    __syncthreads();

    // ---- scatter into bucket-sorted s_V: [R0..R3 | R4 th ch0 ch1 | ch2..4] --
    if (lt < V_) {
        int rk = rkw;
        for (int w = 0; w < (lt >> 6); ++w) rk += s_whist[pk][w][myb];
        int pos = s_start[pk][myb] + rk;
        float th = stg_th[lt];
        float mk = stg_msk[lt];
        float4 f4 = stg_f4[lt];
        float rv = stg_rho[lt];
        float R[5];
        #pragma unroll
        for (int i = 0; i < 5; ++i) {
            float d = rv - s_mu[i];
            R[i] = __expf(-d * d * s_isr[i]);
        }
        *(float4*)&s_V[pk][pos][0] = make_float4(R[0], R[1], R[2], R[3]);
        *(float4*)&s_V[pk][pos][4] = make_float4(R[4], th, f4.x * mk, f4.y * mk);
        *(float4*)&s_V[pk][pos][8] = make_float4(f4.z * mk, f4.w * mk, mk, 0.0f);
    }
    __syncthreads();   // staging overlay dead from here

    // ---- zero all tables (b128) ----
    {
        float4 z4 = make_float4(0.f, 0.f, 0.f, 0.f);
        float4* C4 = (float4*)Cp;
        for (int e = lt; e < CTOT / 4; e += PKT_) C4[e] = z4;
    }
    __syncthreads();

    // ---- G-table build: team of 32 threads per bucket (table = team) ----
    // n = team - 25 + l, l = mq*4+mm < 20; stored slot w = team - 1 + l.
    {
        const int team = lt >> 5, t32 = lt & 31;
        const int cg = t32 / 6;              // channel 0..4 (t32>=30 idle)
        const int mq = t32 - cg * 6;         // 6 m-tiles x 4 slots = 24 >= 20
        const float ist = s_ist1;
        float acc[4][5];
        #pragma unroll
        for (int mm = 0; mm < 4; ++mm)
            #pragma unroll
            for (int i = 0; i < 5; ++i) acc[mm][i] = 0.0f;
        const int v0 = s_start[pk][team], v1 = s_start[pk][team + 1];
        const float nbase = (float)(team - 25 + mq * 4);
        if (cg < 5) {
            for (int v = v0; v < v1; ++v) {
                float4 ra = *(const float4*)&s_V[pk][v][0];
                const float r4 = s_V[pk][v][4];
                const float th = s_V[pk][v][5];
                const float ch = s_V[pk][v][6 + cg];
                float A0 = ch * ra.x, A1 = ch * ra.y, A2 = ch * ra.z,
                      A3 = ch * ra.w, A4 = ch * r4;
                #pragma unroll
                for (int mm = 0; mm < 4; ++mm) {
                    float q = fmaf(nbase + (float)mm, DELTA_F, th);
                    float w = __expf(-q * q * ist);
                    acc[mm][0] = fmaf(w, A0, acc[mm][0]);
                    acc[mm][1] = fmaf(w, A1, acc[mm][1]);
                    acc[mm][2] = fmaf(w, A2, acc[mm][2]);
                    acc[mm][3] = fmaf(w, A3, acc[mm][3]);
                    acc[mm][4] = fmaf(w, A4, acc[mm][4]);
                }
            }
            #pragma unroll
            for (int mm = 0; mm < 4; ++mm) {
                const int l = mq * 4 + mm;             // local slot
                const int w = team - 1 + l;            // stored slot
                if (l < 20 && w >= 0 && w < WSLOTS)
                    #pragma unroll
                    for (int i = 0; i < 5; ++i)
                        Cp[team * CSTR + w * 25 + cg * 5 + i] = acc[mm][i];
            }
        }
    }
    __syncthreads();

    // ---- shift-free prefix: column walk over all 825 element-columns ----
    for (int e = lt; e < CSTR; e += PKT_) {
        float run = Cp[e];                         // table 0 = C[1]
        #pragma unroll
        for (int tk = 1; tk < 16; ++tk) {
            run += Cp[tk * CSTR + e];
            Cp[tk * CSTR + e] = run;
        }
    }
    __syncthreads();

    // ---- gather: 10 flat (r,bin) pairs per thread -> dreg ----
    const float* Tb = Cp + 15 * CSTR;
    float dreg[10];
    #pragma unroll
    for (int it = 0; it < 10; ++it) {
        const int q   = lt + PKT_ * it;            // 0..5119
        const int r   = q / 320;
        const int bin = q - r * 320;
        const int j1 = bin & 15, ci1 = bin >> 4;   // ci1 = c1*5+i1
        const int i1 = ci1 % 5;
        const int sD = ci1, sS = 20 + i1;
        const int wT = r - j1 + 24;                // [9, 39]
        const bool pT = (wT <= 32);
        const int wTc = pT ? wT : 32;
        const float* Tp = Tb + wTc * 25;
        float tD = Tp[sD], tS = Tp[sS];
        float D = pT ? tD : 0.0f;
        float S = pT ? tS : 0.0f;
        if (r > 0) {
            const float* Cr = Cp + (r - 1) * CSTR;
            const float* Up = Cr + wTc * 25;
            float uD = Up[sD], uS = Up[sS];
            if (pT) { D -= uD; S -= uS; }
            const int wW = wT - 16;                // [-7, 23]
            const bool pW = (wW >= 0);
            const int wWc = pW ? wW : 0;
            const float* Wp = Cr + wWc * 25;
            float wD = Wp[sD], wS = Wp[sS];
            if (pW) { D += wD; S += wS; }
        }
        dreg[it] = D / (S + 1e-5f);
    }
    __syncthreads();   // all table reads done -> Cp region reusable

    // ---- overlays in dead table region (per pocket) ----
    float* ring    = Cp;                  // [16][4*RSTR=336] = 5376 floats
    float* s_pool2 = Cp + 5376;           // [4][320] = 1280
    float* s_x1    = Cp + 6656;           // [320]
    float* s_part  = Cp + 6976;           // [640]

    #pragma unroll
    for (int it = 0; it < 10; ++it) {
        const int q   = lt + PKT_ * it;
        const int r   = q / 320;
        const int bin = q - r * 320;
        const int j1 = bin & 15, ci1 = bin >> 4;
        const int c1 = ci1 / 5, i1 = ci1 - c1 * 5;
        ring[r * (4 * RSTR) + c1 * RSTR + i1 * 16 + j1] = dreg[it];
    }
    __syncthreads();

    // ---- conv, u-blocked x4: thread = (rot-quad g, f, u-quad), lt<320 ----
    if (lt < 320) {
        const int g  = lt / 80;               // rotations 4g..4g+3
        const int s  = lt - g * 80;
        const int cf = s / 20;                // f
        const int uq = s - cf * 20;
        const int u0 = uq * 4;
        const float* Wf = W_conv + (size_t)cf * TR_ * TR_ + u0;  // W[cf][k][u0..3]
        const float* r0 = ring + (4 * g) * (4 * RSTR) + cf * RSTR;
        float4 a0 = make_float4(0.f, 0.f, 0.f, 0.f);
        float4 a1 = a0, a2 = a0, a3 = a0;
        #pragma unroll 4
        for (int kq = 0; kq < 20; ++kq) {
            const int k = kq * 4;
            float4 d0 = *(const float4*)&r0[k];
            float4 d1 = *(const float4*)&r0[(4 * RSTR) + k];
            float4 d2 = *(const float4*)&r0[(8 * RSTR) + k];
            float4 d3 = *(const float4*)&r0[(12 * RSTR) + k];
            float4 w0 = *(const float4*)&Wf[(size_t)(k + 0) * TR_];
            float4 w1 = *(const float4*)&Wf[(size_t)(k + 1) * TR_];
            float4 w2 = *(const float4*)&Wf[(size_t)(k + 2) * TR_];
            float4 w3 = *(const float4*)&Wf[(size_t)(k + 3) * TR_];
            a0.x = fmaf(d0.x,w0.x, fmaf(d0.y,w1.x, fmaf(d0.z,w2.x, fmaf(d0.w,w3.x, a0.x))));
            a0.y = fmaf(d0.x,w0.y, fmaf(d0.y,w1.y, fmaf(d0.z,w2.y, fmaf(d0.w,w3.y, a0.y))));
            a0.z = fmaf(d0.x,w0.z, fmaf(d0.y,w1.z, fmaf(d0.z,w2.z, fmaf(d0.w,w3.z, a0.z))));
            a0.w = fmaf(d0.x,w0.w, fmaf(d0.y,w1.w, fmaf(d0.z,w2.w, fmaf(d0.w,w3.w, a0.w))));
            a1.x = fmaf(d1.x,w0.x, fmaf(d1.y,w1.x, fmaf(d1.z,w2.x, fmaf(d1.w,w3.x, a1.x))));
            a1.y = fmaf(d1.x,w0.y, fmaf(d1.y,w1.y, fmaf(d1.z,w2.y, fmaf(d1.w,w3.y, a1.y))));
            a1.z = fmaf(d1.x,w0.z, fmaf(d1.y,w1.z, fmaf(d1.z,w2.z, fmaf(d1.w,w3.z, a1.z))));
            a1.w = fmaf(d1.x,w0.w, fmaf(d1.y,w1.w, fmaf(d1.z,w2.w, fmaf(d1.w,w3.w, a1.w))));
            a2.x = fmaf(d2.x,w0.x, fmaf(d2.y,w1.x, fmaf(d2.z,w2.x, fmaf(d2.w,w3.x, a2.x))));
            a2.y = fmaf(d2.x,w0.y, fmaf(d2.y,w1.y, fmaf(d2.z,w2.y, fmaf(d2.w,w3.y, a2.y))));
            a2.z = fmaf(d2.x,w0.z, fmaf(d2.y,w1.z, fmaf(d2.z,w2.z, fmaf(d2.w,w3.z, a2.z))));
            a2.w = fmaf(d2.x,w0.w, fmaf(d2.y,w1.w, fmaf(d2.z,w2.w, fmaf(d2.w,w3.w, a2.w))));
            a3.x = fmaf(d3.x,w0.x, fmaf(d3.y,w1.x, fmaf(d3.z,w2.x, fmaf(d3.w,w3.x, a3.x))));
            a3.y = fmaf(d3.x,w0.y, fmaf(d3.y,w1.y, fmaf(d3.z,w2.y, fmaf(d3.w,w3.y, a3.y))));
            a3.z = fmaf(d3.x,w0.z, fmaf(d3.y,w1.z, fmaf(d3.z,w2.z, fmaf(d3.w,w3.z, a3.z))));
            a3.w = fmaf(d3.x,w0.w, fmaf(d3.y,w1.w, fmaf(d3.z,w2.w, fmaf(d3.w,w3.w, a3.w))));
        }
        float4 m;
        m.x = fmaxf(fmaxf(a0.x, a1.x), fmaxf(a2.x, a3.x));
        m.y = fmaxf(fmaxf(a0.y, a1.y), fmaxf(a2.y, a3.y));
        m.z = fmaxf(fmaxf(a0.z, a1.z), fmaxf(a2.z, a3.z));
        m.w = fmaxf(fmaxf(a0.w, a1.w), fmaxf(a2.w, a3.w));
        *(float4*)&s_pool2[g * 320 + cf * TR_ + u0] = m;
    }
    __syncthreads();

    // ---- epilogue: maxpool-4 + b_conv + bn1 + relu + W1 + bn2 + relu ----
    if (lt < 320) {
        float best = fmaxf(fmaxf(s_pool2[lt], s_pool2[320 + lt]),
                           fmaxf(s_pool2[640 + lt], s_pool2[960 + lt]));
        best += b_conv[lt];
        float x1 = (best - bn1_m[lt]) * (bn1_g[lt] * rsqrtf(bn1_v[lt] + 1e-3f))
                   + bn1_b[lt];
        s_x1[lt] = fmaxf(x1, 0.0f);
    }
    __syncthreads();
    for (int q = lt; q < 640; q += PKT_) {
        const int c = q / TR_;                 // input chunk 0..7 (40 rows)
        const int ue = q - c * TR_;
        float p = 0.0f;
        const int i0 = c * 40;
        #pragma unroll 8
        for (int i = i0; i < i0 + 40; ++i)
            p = fmaf(s_x1[i], W1[(size_t)i * TR_ + ue], p);
        s_part[q] = p;
    }
    __syncthreads();
    if (lt < TR_) {
        float h = b1[lt];
        #pragma unroll
        for (int c = 0; c < 8; ++c) h += s_part[c * TR_ + lt];
        float x2 = (h - bn2_m[lt]) * (bn2_g[lt] * rsqrtf(bn2_v[lt] + 1e-3f))
                   + bn2_b[lt];
        x2out[(size_t)bp * TR_ + lt] = fmaxf(x2, 0.0f);
    }
}

// ---------------------------------------------------------------------------
// Head, stage A: per (b, chunk c of 10 cov rows): cov chunk + W2 partial.
// ---------------------------------------------------------------------------
__global__ __launch_bounds__(256) void masif_head_partial(
    const float* __restrict__ x2,       // [B*P, 80]
    const float* __restrict__ W2,       // [6400, 64]
    float* __restrict__ hpart)          // [B, 8, 64]
{
    __shared__ __align__(16) float s_x[P_ * TR_];
    __shared__ __align__(16) float s_cov[10 * TR_];
    __shared__ float s_red[4][64];

    const int tid = threadIdx.x;
    const int b = blockIdx.x >> 3, c = blockIdx.x & 7;

    for (int i = tid; i < P_ * TR_; i += 256)
        s_x[i] = x2[(size_t)b * P_ * TR_ + i];
    __syncthreads();

    for (int o = tid; o < 800; o += 256) {
        int il = o / TR_, j = o - il * TR_;
        int i = c * 10 + il;
        float s = 0.0f;
        #pragma unroll 4
        for (int p = 0; p < P_; ++p)
            s = fmaf(s_x[p * TR_ + i], s_x[p * TR_ + j], s);
        s_cov[o] = s * (1.0f / (float)P_);
    }
    __syncthreads();

    {
        const int o = tid & 63, sub = tid >> 6;
        float acc = 0.0f;
        const int q0 = sub * 200;
        const size_t gbase = (size_t)(c * 800) * 64 + o;
        #pragma unroll 8
        for (int q = q0; q < q0 + 200; ++q)
            acc = fmaf(s_cov[q], W2[gbase + (size_t)q * 64], acc);
        s_red[sub][o] = acc;
    }
    __syncthreads();
    if (tid < 64)
        hpart[(size_t)b * 512 + c * 64 + tid] =
            s_red[0][tid] + s_red[1][tid] + s_red[2][tid] + s_red[3][tid];
}

// ---------------------------------------------------------------------------
// Head, stage B: combine chunks, relu, bn3, W3.
// ---------------------------------------------------------------------------
__global__ __launch_bounds__(64) void masif_head_final(
    const float* __restrict__ hpart,
    const float* __restrict__ b2,
    const float* __restrict__ bn3_g, const float* __restrict__ bn3_b,
    const float* __restrict__ bn3_m, const float* __restrict__ bn3_v,
    const float* __restrict__ W3, const float* __restrict__ b3,
    float* __restrict__ out)
{
    __shared__ float s_h[64];
    const int tid = threadIdx.x;
    const int b = blockIdx.x;

    float h = b2[tid];
    #pragma unroll
    for (int c = 0; c < 8; ++c) h += hpart[(size_t)b * 512 + c * 64 + tid];
    h = fmaxf(h, 0.0f);
    s_h[tid] = (h - bn3_m[tid]) * (bn3_g[tid] * rsqrtf(bn3_v[tid] + 1e-3f))
               + bn3_b[tid];
    __syncthreads();

    if (tid < NLIG_) {
        float y = b3[tid];
        #pragma unroll
        for (int k = 0; k < 64; ++k)
            y = fmaf(s_h[k], W3[k * NLIG_ + tid], y);
        out[b * NLIG_ + tid] = y;
    }
}

// ---------------------------------------------------------------------------
extern "C" void kernel_launch(void* const* d_in, const int* in_sizes, int n_in,
                              void* d_out, int out_size, void* d_ws, size_t ws_size,
                              hipStream_t stream)
{
    const float* feat      = (const float*)d_in[0];
    const float* rho       = (const float*)d_in[1];
    const float* theta     = (const float*)d_in[2];
    const float* mask      = (const float*)d_in[3];
    const float* mu_rho    = (const float*)d_in[4];
    const float* sigma_rho = (const float*)d_in[5];
    const float* mu_theta  = (const float*)d_in[6];
    const float* sigma_th  = (const float*)d_in[7];
    const float* W_conv    = (const float*)d_in[8];
    const float* b_conv    = (const float*)d_in[9];
    const float* W1        = (const float*)d_in[10];
    const float* b1        = (const float*)d_in[11];
    const float* bn1_g     = (const float*)d_in[12];
    const float* bn1_b     = (const float*)d_in[13];
    const float* bn1_m     = (const float*)d_in[14];
    const float* bn1_v     = (const float*)d_in[15];
    const float* bn2_g     = (const float*)d_in[16];
    const float* bn2_b     = (const float*)d_in[17];
    const float* bn2_m     = (const float*)d_in[18];
    const float* bn2_v     = (const float*)d_in[19];
    const float* W2        = (const float*)d_in[20];
    const float* b2        = (const float*)d_in[21];
    const float* bn3_g     = (const float*)d_in[22];
    const float* bn3_b     = (const float*)d_in[23];
    const float* bn3_m     = (const float*)d_in[24];
    const float* bn3_v     = (const float*)d_in[25];
    const float* W3        = (const float*)d_in[26];
    const float* b3        = (const float*)d_in[27];

    float* x2ws  = (float*)d_ws;                          // [1024*80]
    float* hpart = (float*)d_ws + (size_t)B_ * P_ * TR_;  // [32*8*64]

    masif_conv_kernel<<<dim3(B_ * P_ / 2), dim3(NTH_), 0, stream>>>(
        feat, rho, theta, mask, mu_rho, sigma_rho, mu_theta, sigma_th,
        W_conv, b_conv, W1, b1,
        bn1_g, bn1_b, bn1_m, bn1_v, bn2_g, bn2_b, bn2_m, bn2_v, x2ws);

    masif_head_partial<<<dim3(B_ * 8), dim3(256), 0, stream>>>(x2ws, W2, hpart);

    masif_head_final<<<dim3(B_), dim3(64), 0, stream>>>(
        hpart, b2, bn3_g, bn3_b, bn3_m, bn3_v, W3, b3, (float*)d_out);
}

// Round 11
// 63.474 us; speedup vs baseline: 1.3181x; 1.0688x over previous
//
#include <hip/hip_runtime.h>
#include <math.h>

#define B_    32
#define P_    32
#define V_    200
#define NF_   4
#define TR_   80
#define NROT_ 16
#define NLIG_ 7
#define NTH_  1024
#define PKT_  512              // threads per pocket (2 pockets per block)

#define WSLOTS 33              // absolute lattice window n in [-24, 8]
#define CSTR   828             // 33*25 = 825 payload + 3 pad (float4 stride)
#define CTOT   (16 * CSTR)     // floats per pocket table block
#define RSTR   84              // ring per-f stride

// f32(2*pi) and f32(2*pi/16): DELTA_F*16 == TWO_PI_F exactly.
static constexpr float TWO_PI_F  = 6.2831854820251465f;
static constexpr float DELTA_F   = 0.39269909262657166f;

// ---------------------------------------------------------------------------
// Conv layer via exact-wrap cumulative theta-lattice tables (see R5 header).
// R9: pocket-pairing (2 pockets / 1024-thread block).  R10:
//  (a) G-build slot-mapping: thread=(bucket,slot), exp computed ONCE and
//      fanned into 25 ci-channels (exps/pocket 24k->4k, same bitwise math);
//  (b) staging in dedicated LDS -> table-zero merged into scatter phase
//      (one barrier and one phase removed);
//  (c) prefix walk float2-vectorized (CSTR padded to 828);
//  (d) classify offsets inline ((float)r * DELTA_F == old s_offs values).
// LDS ~137 KB/block (1 block/CU is scheduler-invariant per R4-R9 evidence).
// ---------------------------------------------------------------------------
__global__ __launch_bounds__(NTH_, 4) void masif_conv_kernel(
    const float* __restrict__ feat, const float* __restrict__ rho,
    const float* __restrict__ theta, const float* __restrict__ mask,
    const float* __restrict__ mu_rho, const float* __restrict__ sigma_rho,
    const float* __restrict__ mu_theta, const float* __restrict__ sigma_theta,
    const float* __restrict__ W_conv, const float* __restrict__ b_conv,
    const float* __restrict__ W1, const float* __restrict__ b1,
    const float* __restrict__ bn1_g, const float* __restrict__ bn1_b,
    const float* __restrict__ bn1_m, const float* __restrict__ bn1_v,
    const float* __restrict__ bn2_g, const float* __restrict__ bn2_b,
    const float* __restrict__ bn2_m, const float* __restrict__ bn2_v,
    float* __restrict__ x2out)
{
    __shared__ __align__(16) float s_C[2][CTOT];     // 105984 B (+overlays)
    __shared__ __align__(16) float s_V[2][V_][12];   //  19200 B
    __shared__ __align__(16) float s_stg[2][1408];   //  11264 B staging
    __shared__ float s_mu[5], s_isr[5];
    __shared__ float s_ist1;
    __shared__ int   s_cnt[2][16], s_start[2][17];
    __shared__ int   s_whist[2][4][16];

    const int tid = threadIdx.x;
    const int pk  = tid >> 9;            // pocket 0/1
    const int lt  = tid & 511;           // lane within pocket
    const int bp  = blockIdx.x * 2 + pk; // pocket id
    const size_t vb = (size_t)bp * V_;

    float* Cp = s_C[pk];                 // pocket table block

    float*  stg_th  = s_stg[pk];              // [200]
    float*  stg_rho = s_stg[pk] + 200;        // [200]
    float*  stg_msk = s_stg[pk] + 400;        // [200]
    float4* stg_f4  = (float4*)(s_stg[pk] + 608);  // [200] float4 (16B aligned)

    for (int i = lt; i < V_; i += PKT_) {
        stg_th[i]  = theta[vb + i];
        stg_rho[i] = rho[vb + i];
        stg_msk[i] = mask[vb + i];
        stg_f4[i]  = ((const float4*)(feat + vb * NF_))[i];
    }
    if (tid < 5) {
        s_mu[tid] = mu_rho[tid * 16];
        float sg = sigma_rho[tid * 16];
        s_isr[tid] = 1.0f / (sg * sg + 1e-5f);
    }
    if (tid == 5) { float sg = sigma_theta[0]; s_ist1 = 1.0f / (sg * sg + 1e-5f); }
    if (tid >= 64 && tid < 96) ((int*)s_cnt)[tid - 64] = 0;
    __syncthreads();

    // ---- classify by exact first-wrap rotation r* (bucket = r*-1) ----
    int myb = 0;
    if (lt < V_) {
        float th = stg_th[lt];
        int rs = 16;
        for (int r = 1; r < 16; ++r) {
            if (th + (float)r * DELTA_F >= TWO_PI_F) { rs = r; break; }  // exact f32
        }
        myb = rs - 1;                         // 0..15
        atomicAdd(&s_cnt[pk][myb], 1);
    }

    // ---- deterministic rank via ballot (pocket waves 0..3 cover lt<256) ----
    int rkw = 0;
    {
        const unsigned long long below = (1ULL << (tid & 63)) - 1ULL;
        const int wv = lt >> 6;               // wave within pocket
        for (int b = 0; b < 16; ++b) {
            bool p = (lt < V_) && (myb == b);
            unsigned long long m = __ballot(p);
            if (p) rkw = __popcll(m & below);
            if (wv < 4 && (tid & 63) == b) s_whist[pk][wv][b] = __popcll(m);
        }
    }
    __syncthreads();
    if (lt == 0) {
        int run = 0;
        for (int k = 0; k < 16; ++k) { s_start[pk][k] = run; run += s_cnt[pk][k]; }
        s_start[pk][16] = run;
    }
    __syncthreads();

    // ---- scatter into bucket-sorted s_V  +  table zero-fill (same phase) ----
    {
        float4 z4 = make_float4(0.f, 0.f, 0.f, 0.f);
        float4* C4 = (float4*)Cp;
        for (int e = lt; e < CTOT / 4; e += PKT_) C4[e] = z4;
    }
    if (lt < V_) {
        int rk = rkw;
        for (int w = 0; w < (lt >> 6); ++w) rk += s_whist[pk][w][myb];
        int pos = s_start[pk][myb] + rk;
        float th = stg_th[lt];
        float mk = stg_msk[lt];
        float4 f4 = stg_f4[lt];
        float rv = stg_rho[lt];
        float R[5];
        #pragma unroll
        for (int i = 0; i < 5; ++i) {
            float d = rv - s_mu[i];
            R[i] = __expf(-d * d * s_isr[i]);
        }
        *(float4*)&s_V[pk][pos][0] = make_float4(R[0], R[1], R[2], R[3]);
        *(float4*)&s_V[pk][pos][4] = make_float4(R[4], th, f4.x * mk, f4.y * mk);
        *(float4*)&s_V[pk][pos][8] = make_float4(f4.z * mk, f4.w * mk, mk, 0.0f);
    }
    __syncthreads();

    // ---- G-table build: thread = (bucket team, stored slot t32) ----
    // active slots w in [team-1, team+18] (n = w-24 in [team-25, team-6]);
    // one exp per (vertex, slot), fanned into 25 ci via 5 mul + 25 FMA.
    {
        const int team = lt >> 5, t32 = lt & 31;
        const int w = team - 1 + t32;                  // t32 < 20 active
        if (t32 < 20 && w >= 0 && w < WSLOTS) {
            const float ist = s_ist1;
            const float nf = (float)(team - 25 + t32); // n = w - 24
            const int v0 = s_start[pk][team], v1 = s_start[pk][team + 1];
            float acc[25];
            #pragma unroll
            for (int i = 0; i < 25; ++i) acc[i] = 0.0f;
            for (int v = v0; v < v1; ++v) {
                float4 ra = *(const float4*)&s_V[pk][v][0];   // R0..R3
                float4 rb = *(const float4*)&s_V[pk][v][4];   // R4 th ch0 ch1
                float4 rc = *(const float4*)&s_V[pk][v][8];   // ch2 ch3 ch4 -
                float q  = fmaf(nf, DELTA_F, rb.y);
                float wg = __expf(-q * q * ist);
                float R[5]  = {ra.x, ra.y, ra.z, ra.w, rb.x};
                float ch[5] = {rb.z, rb.w, rc.x, rc.y, rc.z};
                #pragma unroll
                for (int c = 0; c < 5; ++c) {
                    float t = wg * ch[c];
                    #pragma unroll
                    for (int i = 0; i < 5; ++i)
                        acc[c * 5 + i] = fmaf(t, R[i], acc[c * 5 + i]);
                }
            }
            float* dst = Cp + team * CSTR + w * 25;
            #pragma unroll
            for (int i = 0; i < 25; ++i) dst[i] = acc[i];
        }
    }
    __syncthreads();

    // ---- shift-free prefix: float2 column walk (CSTR/2 = 414 columns) ----
    {
        float2* C2 = (float2*)Cp;
        for (int e = lt; e < CSTR / 2; e += PKT_) {
            float2 run = C2[e];                    // table 0 = C[1]
            #pragma unroll
            for (int tk = 1; tk < 16; ++tk) {
                float2 g = C2[tk * (CSTR / 2) + e];
                run.x += g.x; run.y += g.y;
                C2[tk * (CSTR / 2) + e] = run;
            }
        }
    }
    __syncthreads();

    // ---- gather: 10 flat (r,bin) pairs per thread -> dreg ----
    const float* Tb = Cp + 15 * CSTR;
    float dreg[10];
    #pragma unroll
    for (int it = 0; it < 10; ++it) {
        const int q   = lt + PKT_ * it;            // 0..5119
        const int r   = q / 320;
        const int bin = q - r * 320;
        const int j1 = bin & 15, ci1 = bin >> 4;   // ci1 = c1*5+i1
        const int i1 = ci1 % 5;
        const int sD = ci1, sS = 20 + i1;
        const int wT = r - j1 + 24;                // [9, 39]
        const bool pT = (wT <= 32);
        const int wTc = pT ? wT : 32;
        const float* Tp = Tb + wTc * 25;
        float tD = Tp[sD], tS = Tp[sS];
        float D = pT ? tD : 0.0f;
        float S = pT ? tS : 0.0f;
        if (r > 0) {
            const float* Cr = Cp + (r - 1) * CSTR;
            const float* Up = Cr + wTc * 25;
            float uD = Up[sD], uS = Up[sS];
            if (pT) { D -= uD; S -= uS; }
            const int wW = wT - 16;                // [-7, 23]
            const bool pW = (wW >= 0);
            const int wWc = pW ? wW : 0;
            const float* Wp = Cr + wWc * 25;
            float wD = Wp[sD], wS = Wp[sS];
            if (pW) { D += wD; S += wS; }
        }
        dreg[it] = D / (S + 1e-5f);
    }
    __syncthreads();   // all table reads done -> Cp region reusable

    // ---- overlays in dead table region (per pocket) ----
    float* ring    = Cp;                  // [16][4*RSTR=336] = 5376 floats
    float* s_pool2 = Cp + 5376;           // [4][320] = 1280
    float* s_x1    = Cp + 6656;           // [320]
    float* s_part  = Cp + 6976;           // [640]

    #pragma unroll
    for (int it = 0; it < 10; ++it) {
        const int q   = lt + PKT_ * it;
        const int r   = q / 320;
        const int bin = q - r * 320;
        const int j1 = bin & 15, ci1 = bin >> 4;
        const int c1 = ci1 / 5, i1 = ci1 - c1 * 5;
        ring[r * (4 * RSTR) + c1 * RSTR + i1 * 16 + j1] = dreg[it];
    }
    __syncthreads();

    // ---- conv, u-blocked x4: thread = (rot-quad g, f, u-quad), lt<320 ----
    if (lt < 320) {
        const int g  = lt / 80;               // rotations 4g..4g+3
        const int s  = lt - g * 80;
        const int cf = s / 20;                // f
        const int uq = s - cf * 20;
        const int u0 = uq * 4;
        const float* Wf = W_conv + (size_t)cf * TR_ * TR_ + u0;  // W[cf][k][u0..3]
        const float* r0 = ring + (4 * g) * (4 * RSTR) + cf * RSTR;
        float4 a0 = make_float4(0.f, 0.f, 0.f, 0.f);
        float4 a1 = a0, a2 = a0, a3 = a0;
        #pragma unroll 4
        for (int kq = 0; kq < 20; ++kq) {
            const int k = kq * 4;
            float4 d0 = *(const float4*)&r0[k];
            float4 d1 = *(const float4*)&r0[(4 * RSTR) + k];
            float4 d2 = *(const float4*)&r0[(8 * RSTR) + k];
            float4 d3 = *(const float4*)&r0[(12 * RSTR) + k];
            float4 w0 = *(const float4*)&Wf[(size_t)(k + 0) * TR_];
            float4 w1 = *(const float4*)&Wf[(size_t)(k + 1) * TR_];
            float4 w2 = *(const float4*)&Wf[(size_t)(k + 2) * TR_];
            float4 w3 = *(const float4*)&Wf[(size_t)(k + 3) * TR_];
            a0.x = fmaf(d0.x,w0.x, fmaf(d0.y,w1.x, fmaf(d0.z,w2.x, fmaf(d0.w,w3.x, a0.x))));
            a0.y = fmaf(d0.x,w0.y, fmaf(d0.y,w1.y, fmaf(d0.z,w2.y, fmaf(d0.w,w3.y, a0.y))));
            a0.z = fmaf(d0.x,w0.z, fmaf(d0.y,w1.z, fmaf(d0.z,w2.z, fmaf(d0.w,w3.z, a0.z))));
            a0.w = fmaf(d0.x,w0.w, fmaf(d0.y,w1.w, fmaf(d0.z,w2.w, fmaf(d0.w,w3.w, a0.w))));
            a1.x = fmaf(d1.x,w0.x, fmaf(d1.y,w1.x, fmaf(d1.z,w2.x, fmaf(d1.w,w3.x, a1.x))));
            a1.y = fmaf(d1.x,w0.y, fmaf(d1.y,w1.y, fmaf(d1.z,w2.y, fmaf(d1.w,w3.y, a1.y))));
            a1.z = fmaf(d1.x,w0.z, fmaf(d1.y,w1.z, fmaf(d1.z,w2.z, fmaf(d1.w,w3.z, a1.z))));
            a1.w = fmaf(d1.x,w0.w, fmaf(d1.y,w1.w, fmaf(d1.z,w2.w, fmaf(d1.w,w3.w, a1.w))));
            a2.x = fmaf(d2.x,w0.x, fmaf(d2.y,w1.x, fmaf(d2.z,w2.x, fmaf(d2.w,w3.x, a2.x))));
            a2.y = fmaf(d2.x,w0.y, fmaf(d2.y,w1.y, fmaf(d2.z,w2.y, fmaf(d2.w,w3.y, a2.y))));
            a2.z = fmaf(d2.x,w0.z, fmaf(d2.y,w1.z, fmaf(d2.z,w2.z, fmaf(d2.w,w3.z, a2.z))));
            a2.w = fmaf(d2.x,w0.w, fmaf(d2.y,w1.w, fmaf(d2.z,w2.w, fmaf(d2.w,w3.w, a2.w))));
            a3.x = fmaf(d3.x,w0.x, fmaf(d3.y,w1.x, fmaf(d3.z,w2.x, fmaf(d3.w,w3.x, a3.x))));
            a3.y = fmaf(d3.x,w0.y, fmaf(d3.y,w1.y, fmaf(d3.z,w2.y, fmaf(d3.w,w3.y, a3.y))));
            a3.z = fmaf(d3.x,w0.z, fmaf(d3.y,w1.z, fmaf(d3.z,w2.z, fmaf(d3.w,w3.z, a3.z))));
            a3.w = fmaf(d3.x,w0.w, fmaf(d3.y,w1.w, fmaf(d3.z,w2.w, fmaf(d3.w,w3.w, a3.w))));
        }
        float4 m;
        m.x = fmaxf(fmaxf(a0.x, a1.x), fmaxf(a2.x, a3.x));
        m.y = fmaxf(fmaxf(a0.y, a1.y), fmaxf(a2.y, a3.y));
        m.z = fmaxf(fmaxf(a0.z, a1.z), fmaxf(a2.z, a3.z));
        m.w = fmaxf(fmaxf(a0.w, a1.w), fmaxf(a2.w, a3.w));
        *(float4*)&s_pool2[g * 320 + cf * TR_ + u0] = m;
    }
    __syncthreads();

    // ---- epilogue: maxpool-4 + b_conv + bn1 + relu + W1 + bn2 + relu ----
    if (lt < 320) {
        float best = fmaxf(fmaxf(s_pool2[lt], s_pool2[320 + lt]),
                           fmaxf(s_pool2[640 + lt], s_pool2[960 + lt]));
        best += b_conv[lt];
        float x1 = (best - bn1_m[lt]) * (bn1_g[lt] * rsqrtf(bn1_v[lt] + 1e-3f))
                   + bn1_b[lt];
        s_x1[lt] = fmaxf(x1, 0.0f);
    }
    __syncthreads();
    for (int q = lt; q < 640; q += PKT_) {
        const int c = q / TR_;                 // input chunk 0..7 (40 rows)
        const int ue = q - c * TR_;
        float p = 0.0f;
        const int i0 = c * 40;
        #pragma unroll 8
        for (int i = i0; i < i0 + 40; ++i)
            p = fmaf(s_x1[i], W1[(size_t)i * TR_ + ue], p);
        s_part[q] = p;
    }
    __syncthreads();
    if (lt < TR_) {
        float h = b1[lt];
        #pragma unroll
        for (int c = 0; c < 8; ++c) h += s_part[c * TR_ + lt];
        float x2 = (h - bn2_m[lt]) * (bn2_g[lt] * rsqrtf(bn2_v[lt] + 1e-3f))
                   + bn2_b[lt];
        x2out[(size_t)bp * TR_ + lt] = fmaxf(x2, 0.0f);
    }
}

// ---------------------------------------------------------------------------
// Head, stage A: per (b, chunk c of 10 cov rows): cov chunk + W2 partial.
// ---------------------------------------------------------------------------
__global__ __launch_bounds__(256) void masif_head_partial(
    const float* __restrict__ x2,       // [B*P, 80]
    const float* __restrict__ W2,       // [6400, 64]
    float* __restrict__ hpart)          // [B, 8, 64]
{
    __shared__ __align__(16) float s_x[P_ * TR_];
    __shared__ __align__(16) float s_cov[10 * TR_];
    __shared__ float s_red[4][64];

    const int tid = threadIdx.x;
    const int b = blockIdx.x >> 3, c = blockIdx.x & 7;

    for (int i = tid; i < P_ * TR_; i += 256)
        s_x[i] = x2[(size_t)b * P_ * TR_ + i];
    __syncthreads();

    for (int o = tid; o < 800; o += 256) {
        int il = o / TR_, j = o - il * TR_;
        int i = c * 10 + il;
        float s = 0.0f;
        #pragma unroll 4
        for (int p = 0; p < P_; ++p)
            s = fmaf(s_x[p * TR_ + i], s_x[p * TR_ + j], s);
        s_cov[o] = s * (1.0f / (float)P_);
    }
    __syncthreads();

    {
        const int o = tid & 63, sub = tid >> 6;
        float acc = 0.0f;
        const int q0 = sub * 200;
        const size_t gbase = (size_t)(c * 800) * 64 + o;
        #pragma unroll 8
        for (int q = q0; q < q0 + 200; ++q)
            acc = fmaf(s_cov[q], W2[gbase + (size_t)q * 64], acc);
        s_red[sub][o] = acc;
    }
    __syncthreads();
    if (tid < 64)
        hpart[(size_t)b * 512 + c * 64 + tid] =
            s_red[0][tid] + s_red[1][tid] + s_red[2][tid] + s_red[3][tid];
}

// ---------------------------------------------------------------------------
// Head, stage B: combine chunks, relu, bn3, W3.
// ---------------------------------------------------------------------------
__global__ __launch_bounds__(64) void masif_head_final(
    const float* __restrict__ hpart,
    const float* __restrict__ b2,
    const float* __restrict__ bn3_g, const float* __restrict__ bn3_b,
    const float* __restrict__ bn3_m, const float* __restrict__ bn3_v,
    const float* __restrict__ W3, const float* __restrict__ b3,
    float* __restrict__ out)
{
    __shared__ float s_h[64];
    const int tid = threadIdx.x;
    const int b = blockIdx.x;

    float h = b2[tid];
    #pragma unroll
    for (int c = 0; c < 8; ++c) h += hpart[(size_t)b * 512 + c * 64 + tid];
    h = fmaxf(h, 0.0f);
    s_h[tid] = (h - bn3_m[tid]) * (bn3_g[tid] * rsqrtf(bn3_v[tid] + 1e-3f))
               + bn3_b[tid];
    __syncthreads();

    if (tid < NLIG_) {
        float y = b3[tid];
        #pragma unroll
        for (int k = 0; k < 64; ++k)
            y = fmaf(s_h[k], W3[k * NLIG_ + tid], y);
        out[b * NLIG_ + tid] = y;
    }
}

// ---------------------------------------------------------------------------
extern "C" void kernel_launch(void* const* d_in, const int* in_sizes, int n_in,
                              void* d_out, int out_size, void* d_ws, size_t ws_size,
                              hipStream_t stream)
{
    const float* feat      = (const float*)d_in[0];
    const float* rho       = (const float*)d_in[1];
    const float* theta     = (const float*)d_in[2];
    const float* mask      = (const float*)d_in[3];
    const float* mu_rho    = (const float*)d_in[4];
    const float* sigma_rho = (const float*)d_in[5];
    const float* mu_theta  = (const float*)d_in[6];
    const float* sigma_th  = (const float*)d_in[7];
    const float* W_conv    = (const float*)d_in[8];
    const float* b_conv    = (const float*)d_in[9];
    const float* W1        = (const float*)d_in[10];
    const float* b1        = (const float*)d_in[11];
    const float* bn1_g     = (const float*)d_in[12];
    const float* bn1_b     = (const float*)d_in[13];
    const float* bn1_m     = (const float*)d_in[14];
    const float* bn1_v     = (const float*)d_in[15];
    const float* bn2_g     = (const float*)d_in[16];
    const float* bn2_b     = (const float*)d_in[17];
    const float* bn2_m     = (const float*)d_in[18];
    const float* bn2_v     = (const float*)d_in[19];
    const float* W2        = (const float*)d_in[20];
    const float* b2        = (const float*)d_in[21];
    const float* bn3_g     = (const float*)d_in[22];
    const float* bn3_b     = (const float*)d_in[23];
    const float* bn3_m     = (const float*)d_in[24];
    const float* bn3_v     = (const float*)d_in[25];
    const float* W3        = (const float*)d_in[26];
    const float* b3        = (const float*)d_in[27];

    float* x2ws  = (float*)d_ws;                          // [1024*80]
    float* hpart = (float*)d_ws + (size_t)B_ * P_ * TR_;  // [32*8*64]

    masif_conv_kernel<<<dim3(B_ * P_ / 2), dim3(NTH_), 0, stream>>>(
        feat, rho, theta, mask, mu_rho, sigma_rho, mu_theta, sigma_th,
        W_conv, b_conv, W1, b1,
        bn1_g, bn1_b, bn1_m, bn1_v, bn2_g, bn2_b, bn2_m, bn2_v, x2ws);

    masif_head_partial<<<dim3(B_ * 8), dim3(256), 0, stream>>>(x2ws, W2, hpart);

    masif_head_final<<<dim3(B_), dim3(64), 0, stream>>>(
        hpart, b2, bn3_g, bn3_b, bn3_m, bn3_v, W3, b3, (float*)d_out);
}